// Round 1
// baseline (1386.515 us; speedup 1.0000x reference)
//
#include <hip/hip_runtime.h>
#include <cstdint>

typedef __bf16 bf16;
typedef bf16 bf16x8 __attribute__((ext_vector_type(8)));
typedef float f32x4 __attribute__((ext_vector_type(4)));

constexpr int kB = 2, kS = 1024, kD = 1024, kNH = 16, kHD = 64, kE = 8, kHID = 4096;
constexpr int kT = kB * kS;        // 2048 tokens
constexpr int kSlots = kT * 2;     // 4096 token-expert assignments (TOPK=2)
constexpr float kEPS = 1e-6f;

#define BM 128
#define BN 128
#define BK 32

// ---------------- RMSNorm: fp32 in -> bf16 out (+ optional rstd for gate) ----------------
__global__ __launch_bounds__(256) void rmsnorm_kernel(const float* __restrict__ x,
                                                      const float* __restrict__ w,
                                                      bf16* __restrict__ out,
                                                      float* __restrict__ rstd_out) {
  int t = blockIdx.x;
  int tid = threadIdx.x;
  const float4* xr = (const float4*)(x + (size_t)t * kD);
  float4 xv = xr[tid];
  float ss = xv.x * xv.x + xv.y * xv.y + xv.z * xv.z + xv.w * xv.w;
  for (int off = 32; off >= 1; off >>= 1) ss += __shfl_xor(ss, off, 64);
  __shared__ float red[4];
  int w64 = tid >> 6, lane = tid & 63;
  if (lane == 0) red[w64] = ss;
  __syncthreads();
  float tot = red[0] + red[1] + red[2] + red[3];
  float rstd = rsqrtf(tot / (float)kD + kEPS);
  const float4* wr = (const float4*)w;
  float4 wv = wr[tid];
  bf16* op = out + (size_t)t * kD + tid * 4;
  op[0] = (bf16)(xv.x * wv.x * rstd);
  op[1] = (bf16)(xv.y * wv.y * rstd);
  op[2] = (bf16)(xv.z * wv.z * rstd);
  op[3] = (bf16)(xv.w * wv.w * rstd);
  if (rstd_out && tid == 0) rstd_out[t] = rstd;
}

// ---------------- Generic NT GEMM: C[m,n] = sum_k A_bf16[m,k] * W_f32[n,k] ----------------
// Dense mode (counts==null): z in {0,1,2} selects (W0,C0)/(W1,C1)/(W2,C2), M=Mfix.
// Expert mode (counts!=null): z = expert id; W = W0 + z*wstride; C = C0;
//   rows are [offsets[z], offsets[z]+counts[z]); A row via gather[] (or slot id).
__global__ __launch_bounds__(256) void gemm_bt(
    const bf16* __restrict__ A, int lda,
    const float* __restrict__ W0, const float* __restrict__ W1, const float* __restrict__ W2,
    long wstride, int ldw,
    void* __restrict__ C0, void* __restrict__ C1, void* __restrict__ C2,
    int ldc, int c_bf16,
    int Mfix, int N, int K,
    const int* __restrict__ counts, const int* __restrict__ offsets,
    const int* __restrict__ gather,
    const float* __restrict__ rowscale, const float* __restrict__ residual) {
  int z = blockIdx.z;
  const float* W = W0;
  void* C = C0;
  int cnt = Mfix, base = 0;
  if (counts) {
    cnt = counts[z];
    base = offsets[z];
    W = W0 + (long)z * wstride;
  } else {
    if (z == 1) { W = W1; C = C1; }
    else if (z == 2) { W = W2; C = C2; }
  }
  int m0 = blockIdx.y * BM;
  if (m0 >= cnt) return;
  int n0 = blockIdx.x * BN;

  __shared__ __align__(16) bf16 As[BM * BK];
  __shared__ __align__(16) bf16 Ws[BN * BK];

  int tid = threadIdx.x;
  int sr = tid >> 1;            // 0..127
  int sc = (tid & 1) * 16;      // 0 or 16

  // resolve A row for staging
  int am = m0 + sr;
  int amc = (am < cnt) ? am : (cnt - 1);
  long arow;
  if (counts) {
    arow = gather ? (long)gather[base + amc] : (long)(base + amc);
  } else {
    arow = am;
  }
  const bf16* abase = A + arow * (long)lda + sc;
  const float* wbase = W + (long)(n0 + sr) * ldw + sc;

  int w = tid >> 6, lane = tid & 63;
  int wr = (w >> 1) * 64, wc = (w & 1) * 64;
  int r = lane & 15, q = lane >> 4;

  f32x4 acc[4][4];
#pragma unroll
  for (int i = 0; i < 4; ++i)
#pragma unroll
    for (int j = 0; j < 4; ++j) acc[i][j] = (f32x4){0.f, 0.f, 0.f, 0.f};

  for (int k0 = 0; k0 < K; k0 += BK) {
    // stage A (bf16 passthrough, 32B/thread)
    *(uint4*)&As[sr * BK + sc] = *(const uint4*)(abase + k0);
    *(uint4*)&As[sr * BK + sc + 8] = *(const uint4*)(abase + k0 + 8);
    // stage W (fp32 -> bf16 inline)
    const float4* wp = (const float4*)(wbase + k0);
    float4 f0 = wp[0], f1 = wp[1], f2 = wp[2], f3 = wp[3];
    bf16x8 w0, w1;
    w0[0] = (bf16)f0.x; w0[1] = (bf16)f0.y; w0[2] = (bf16)f0.z; w0[3] = (bf16)f0.w;
    w0[4] = (bf16)f1.x; w0[5] = (bf16)f1.y; w0[6] = (bf16)f1.z; w0[7] = (bf16)f1.w;
    w1[0] = (bf16)f2.x; w1[1] = (bf16)f2.y; w1[2] = (bf16)f2.z; w1[3] = (bf16)f2.w;
    w1[4] = (bf16)f3.x; w1[5] = (bf16)f3.y; w1[6] = (bf16)f3.z; w1[7] = (bf16)f3.w;
    *(bf16x8*)&Ws[sr * BK + sc] = w0;
    *(bf16x8*)&Ws[sr * BK + sc + 8] = w1;
    __syncthreads();

    bf16x8 af[4], bfr[4];
#pragma unroll
    for (int i = 0; i < 4; ++i) af[i] = *(const bf16x8*)&As[(wr + i * 16 + r) * BK + q * 8];
#pragma unroll
    for (int j = 0; j < 4; ++j) bfr[j] = *(const bf16x8*)&Ws[(wc + j * 16 + r) * BK + q * 8];
#pragma unroll
    for (int i = 0; i < 4; ++i)
#pragma unroll
      for (int j = 0; j < 4; ++j)
        acc[i][j] = __builtin_amdgcn_mfma_f32_16x16x32_bf16(af[i], bfr[j], acc[i][j], 0, 0, 0);
    __syncthreads();
  }

  // epilogue: C/D layout col=lane&15, row=quad*4+reg
#pragma unroll
  for (int i = 0; i < 4; ++i)
#pragma unroll
    for (int j = 0; j < 4; ++j) {
      int col = n0 + wc + j * 16 + r;
#pragma unroll
      for (int rg = 0; rg < 4; ++rg) {
        int m = m0 + wr + i * 16 + q * 4 + rg;
        if (m >= cnt) continue;
        long crow = base + m;
        float v = acc[i][j][rg];
        if (rowscale) v *= rowscale[crow];
        if (residual) v += residual[crow * (long)ldc + col];
        if (c_bf16) ((bf16*)C)[crow * (long)ldc + col] = (bf16)v;
        else ((float*)C)[crow * (long)ldc + col] = v;
      }
    }
}

// ---------------- RoPE in-place on q,k (fp32, [t][h*64+d]) ----------------
__global__ __launch_bounds__(256) void rope_kernel(float* __restrict__ qf, float* __restrict__ kf) {
  int id = blockIdx.x * 256 + threadIdx.x;  // kT*kNH*32 threads
  int j = id & 31;
  int h = (id >> 5) & (kNH - 1);
  int t = id >> 9;
  int s = t & (kS - 1);
  // inv_freq = 10000^(-j/32) = exp(-ln(10000)*j/32)
  float inv = expf(-9.210340371976184f * (float)j * (1.0f / 32.0f));
  float fr = (float)s * inv;
  float c = cosf(fr), sn = sinf(fr);
  size_t idx = (size_t)t * kD + h * kHD + j;
  float x1 = qf[idx], x2 = qf[idx + 32];
  qf[idx] = x1 * c - x2 * sn;
  qf[idx + 32] = x2 * c + x1 * sn;
  float y1 = kf[idx], y2 = kf[idx + 32];
  kf[idx] = y1 * c - y2 * sn;
  kf[idx + 32] = y2 * c + y1 * sn;
}

// ---------------- Causal flash attention (fp32 vector), out bf16 ----------------
// grid (S/64, NH, B), 256 threads = 4 waves; wave handles 16 q rows;
// lane = (g,r): r=row-in-16, g=dim-group (16 dims each of HD=64).
__global__ __launch_bounds__(256) void attn_kernel(const float* __restrict__ qf,
                                                   const float* __restrict__ kf,
                                                   const float* __restrict__ vf,
                                                   bf16* __restrict__ o) {
  int qt = blockIdx.x, h = blockIdx.y, b = blockIdx.z;
  __shared__ float Ks[64 * 64];
  __shared__ float Vs[64 * 64];
  int tid = threadIdx.x, w = tid >> 6, lane = tid & 63;
  int r = lane & 15, g = lane >> 4;
  int sq = qt * 64 + w * 16 + r;
  const float4* qp = (const float4*)(qf + ((size_t)(b * kS + sq) * kD + h * kHD + g * 16));
  float4 q0 = qp[0], q1 = qp[1], q2 = qp[2], q3 = qp[3];
  const float scl = 0.125f;  // 1/sqrt(64)
  q0.x *= scl; q0.y *= scl; q0.z *= scl; q0.w *= scl;
  q1.x *= scl; q1.y *= scl; q1.z *= scl; q1.w *= scl;
  q2.x *= scl; q2.y *= scl; q2.z *= scl; q2.w *= scl;
  q3.x *= scl; q3.y *= scl; q3.z *= scl; q3.w *= scl;
  float oa[16];
#pragma unroll
  for (int d = 0; d < 16; ++d) oa[d] = 0.f;
  float mrun = -1e30f, lrun = 0.f;
  int srow = tid >> 2, scol = (tid & 3) * 16;
  for (int kt = 0; kt <= qt; ++kt) {
    const float4* kp = (const float4*)(kf + ((size_t)(b * kS + kt * 64 + srow) * kD + h * kHD + scol));
    const float4* vp = (const float4*)(vf + ((size_t)(b * kS + kt * 64 + srow) * kD + h * kHD + scol));
    float4* ksd = (float4*)&Ks[srow * 64 + scol];
    float4* vsd = (float4*)&Vs[srow * 64 + scol];
    ksd[0] = kp[0]; ksd[1] = kp[1]; ksd[2] = kp[2]; ksd[3] = kp[3];
    vsd[0] = vp[0]; vsd[1] = vp[1]; vsd[2] = vp[2]; vsd[3] = vp[3];
    __syncthreads();
    int jmax = (kt == qt) ? (w * 16 + r + 1) : 64;
    for (int jj = 0; jj < 64; ++jj) {
      const float4* kv = (const float4*)&Ks[jj * 64 + g * 16];
      float4 k0 = kv[0], k1 = kv[1], k2 = kv[2], k3 = kv[3];
      float s = q0.x * k0.x + q0.y * k0.y + q0.z * k0.z + q0.w * k0.w
              + q1.x * k1.x + q1.y * k1.y + q1.z * k1.z + q1.w * k1.w
              + q2.x * k2.x + q2.y * k2.y + q2.z * k2.z + q2.w * k2.w
              + q3.x * k3.x + q3.y * k3.y + q3.z * k3.z + q3.w * k3.w;
      s += __shfl_xor(s, 16, 64);
      s += __shfl_xor(s, 32, 64);
      if (jj >= jmax) s = -1e30f;
      float mnew = fmaxf(mrun, s);
      float alpha = __expf(mrun - mnew);
      float p = __expf(s - mnew);
      lrun = lrun * alpha + p;
      const float4* vv = (const float4*)&Vs[jj * 64 + g * 16];
      float4 v0 = vv[0], v1 = vv[1], v2 = vv[2], v3 = vv[3];
      oa[0] = oa[0] * alpha + p * v0.x;  oa[1] = oa[1] * alpha + p * v0.y;
      oa[2] = oa[2] * alpha + p * v0.z;  oa[3] = oa[3] * alpha + p * v0.w;
      oa[4] = oa[4] * alpha + p * v1.x;  oa[5] = oa[5] * alpha + p * v1.y;
      oa[6] = oa[6] * alpha + p * v1.z;  oa[7] = oa[7] * alpha + p * v1.w;
      oa[8] = oa[8] * alpha + p * v2.x;  oa[9] = oa[9] * alpha + p * v2.y;
      oa[10] = oa[10] * alpha + p * v2.z; oa[11] = oa[11] * alpha + p * v2.w;
      oa[12] = oa[12] * alpha + p * v3.x; oa[13] = oa[13] * alpha + p * v3.y;
      oa[14] = oa[14] * alpha + p * v3.z; oa[15] = oa[15] * alpha + p * v3.w;
      mrun = mnew;
    }
    __syncthreads();
  }
  float invl = 1.f / lrun;
  bf16* op = o + ((size_t)(b * kS + sq) * kD + h * kHD + g * 16);
#pragma unroll
  for (int d = 0; d < 16; ++d) op[d] = (bf16)(oa[d] * invl);
}

// ---------------- zero the small counters ----------------
__global__ void zero_kernel(int* counts, float* sumg, float* sump) {
  int i = threadIdx.x;
  if (i < kE) { counts[i] = 0; sumg[i] = 0.f; sump[i] = 0.f; }
}

// ---------------- Gate: fp32 logits from h (pre-norm) * ffn_w * rstd; top-2 ----------------
__global__ __launch_bounds__(64) void gate_kernel(const float* __restrict__ h,
                                                  const float* __restrict__ ffnw,
                                                  const float* __restrict__ rstd,
                                                  const float* __restrict__ gw,
                                                  int* __restrict__ counts,
                                                  float* __restrict__ sumg, float* __restrict__ sump,
                                                  int* __restrict__ top_idx, float* __restrict__ top_gate) {
  int t = blockIdx.x;
  int lane = threadIdx.x;
  int e = lane >> 3, c = lane & 7;
  const float4* hp = (const float4*)(h + (size_t)t * kD + c * 128);
  const float4* wp = (const float4*)(ffnw + c * 128);
  const float4* gp = (const float4*)(gw + (size_t)e * kD + c * 128);
  float sum = 0.f;
#pragma unroll 8
  for (int i = 0; i < 32; ++i) {
    float4 a = hp[i], b = wp[i], g4 = gp[i];
    sum += a.x * b.x * g4.x + a.y * b.y * g4.y + a.z * b.z * g4.z + a.w * b.w * g4.w;
  }
  sum += __shfl_xor(sum, 1, 64);
  sum += __shfl_xor(sum, 2, 64);
  sum += __shfl_xor(sum, 4, 64);
  __shared__ float lg[kE];
  if (c == 0) lg[e] = sum * rstd[t];
  __syncthreads();
  if (lane == 0) {
    float l[kE];
#pragma unroll
    for (int i = 0; i < kE; ++i) l[i] = lg[i];
    int i1 = 0;
#pragma unroll
    for (int i = 1; i < kE; ++i) if (l[i] > l[i1]) i1 = i;
    int i2 = (i1 == 0) ? 1 : 0;
#pragma unroll
    for (int i = 0; i < kE; ++i) if (i != i1 && l[i] > l[i2]) i2 = i;
    float e2 = __expf(l[i2] - l[i1]);
    float g1 = 1.f / (1.f + e2);
    float g2 = e2 / (1.f + e2);
    float pm = l[i1];
    float pr[kE], ps = 0.f;
#pragma unroll
    for (int i = 0; i < kE; ++i) { pr[i] = __expf(l[i] - pm); ps += pr[i]; }
    float pinv = 1.f / ps;
#pragma unroll
    for (int i = 0; i < kE; ++i) atomicAdd(&sump[i], pr[i] * pinv);
    atomicAdd(&sumg[i1], g1);
    atomicAdd(&sumg[i2], g2);
    atomicAdd(&counts[i1], 1);
    atomicAdd(&counts[i2], 1);
    top_idx[2 * t] = i1; top_idx[2 * t + 1] = i2;
    top_gate[2 * t] = g1; top_gate[2 * t + 1] = g2;
  }
}

// ---------------- offsets + cursors + aux loss ----------------
__global__ void offsets_aux_kernel(const int* counts, int* offs, int* cur,
                                   const float* sumg, const float* sump, float* out_aux) {
  if (threadIdx.x == 0 && blockIdx.x == 0) {
    int acc = 0;
    for (int e = 0; e < kE; ++e) { offs[e] = acc; cur[e] = acc; acc += counts[e]; }
    float aux = 0.f;
    for (int e = 0; e < kE; ++e) aux += (sumg[e] / (float)kT) * (sump[e] / (float)kT);
    out_aux[0] = (float)kE * aux;
  }
}

// ---------------- scatter token->slot ----------------
__global__ __launch_bounds__(256) void scatter_kernel(const int* __restrict__ top_idx,
                                                      const float* __restrict__ top_gate,
                                                      int* __restrict__ cur,
                                                      int* __restrict__ assign_token,
                                                      float* __restrict__ assign_gate,
                                                      int* __restrict__ tok_slot) {
  int id = blockIdx.x * 256 + threadIdx.x;
  if (id >= kSlots) return;
  int e = top_idx[id];
  int slot = atomicAdd(&cur[e], 1);
  assign_token[slot] = id >> 1;
  assign_gate[slot] = top_gate[id];
  tok_slot[id] = slot;
}

// ---------------- silu(g)*u elementwise, in-place into g ----------------
__global__ __launch_bounds__(256) void silu_mul_kernel(bf16* __restrict__ gbuf, const bf16* __restrict__ ubuf) {
  size_t id = ((size_t)blockIdx.x * 256 + threadIdx.x) * 8;
  bf16x8 gv = *(bf16x8*)(gbuf + id);
  bf16x8 uv = *(const bf16x8*)(ubuf + id);
  bf16x8 ov;
#pragma unroll
  for (int i = 0; i < 8; ++i) {
    float gf = (float)gv[i], uf = (float)uv[i];
    float sig = 1.f / (1.f + __expf(-gf));
    ov[i] = (bf16)(gf * sig * uf);
  }
  *(bf16x8*)(gbuf + id) = ov;
}

// ---------------- final: out = h + down[slot0] + down[slot1] (gates pre-applied) ----------------
__global__ __launch_bounds__(256) void final_kernel(const float* __restrict__ h,
                                                    const float* __restrict__ down,
                                                    const int* __restrict__ tok_slot,
                                                    float* __restrict__ out) {
  int t = blockIdx.x, tid = threadIdx.x;
  int s0 = tok_slot[2 * t], s1 = tok_slot[2 * t + 1];
  const float4* hp = (const float4*)(h + (size_t)t * kD);
  const float4* d0 = (const float4*)(down + (size_t)s0 * kD);
  const float4* d1 = (const float4*)(down + (size_t)s1 * kD);
  float4 a = hp[tid], b0 = d0[tid], b1 = d1[tid];
  float4 rv;
  rv.x = a.x + b0.x + b1.x;
  rv.y = a.y + b0.y + b1.y;
  rv.z = a.z + b0.z + b1.z;
  rv.w = a.w + b0.w + b1.w;
  ((float4*)(out + (size_t)t * kD))[tid] = rv;
}

extern "C" void kernel_launch(void* const* d_in, const int* in_sizes, int n_in,
                              void* d_out, int out_size, void* d_ws, size_t ws_size,
                              hipStream_t stream) {
  const float* x = (const float*)d_in[0];
  const float* wq = (const float*)d_in[1];
  const float* wk = (const float*)d_in[2];
  const float* wv = (const float*)d_in[3];
  const float* wo = (const float*)d_in[4];
  const float* attn_w = (const float*)d_in[5];
  const float* ffn_w = (const float*)d_in[6];
  const float* gate_w = (const float*)d_in[7];
  const float* wg = (const float*)d_in[8];
  const float* wu = (const float*)d_in[9];
  const float* wd = (const float*)d_in[10];
  float* out = (float*)d_out;

  char* ws = (char*)d_ws;
  size_t off = 0;
  auto alloc = [&](size_t bytes) -> void* {
    void* p = ws + off;
    off = (off + bytes + 255) & ~(size_t)255;
    return p;
  };
  bf16* xn = (bf16*)alloc((size_t)kT * kD * 2);
  float* qf = (float*)alloc((size_t)kT * kD * 4);
  float* kf = (float*)alloc((size_t)kT * kD * 4);
  float* vf = (float*)alloc((size_t)kT * kD * 4);
  bf16* attn_o = (bf16*)alloc((size_t)kT * kD * 2);
  float* hbuf = (float*)alloc((size_t)kT * kD * 4);
  bf16* hn = (bf16*)alloc((size_t)kT * kD * 2);
  float* rstd = (float*)alloc((size_t)kT * 4);
  int* counts = (int*)alloc(kE * 4);
  int* cur = (int*)alloc(kE * 4);
  int* offs = (int*)alloc(kE * 4);
  float* sumg = (float*)alloc(kE * 4);
  float* sump = (float*)alloc(kE * 4);
  int* top_idx = (int*)alloc((size_t)kSlots * 4);
  float* top_gate = (float*)alloc((size_t)kSlots * 4);
  int* assign_token = (int*)alloc((size_t)kSlots * 4);
  float* assign_gate = (float*)alloc((size_t)kSlots * 4);
  int* tok_slot = (int*)alloc((size_t)kSlots * 4);
  bf16* gbuf = (bf16*)alloc((size_t)kSlots * kHID * 2);
  bf16* ubuf = (bf16*)alloc((size_t)kSlots * kHID * 2);
  float* down = (float*)alloc((size_t)kSlots * kD * 4);
  (void)ws_size; (void)n_in; (void)in_sizes; (void)out_size;

  // 1. zero counters
  zero_kernel<<<1, 64, 0, stream>>>(counts, sumg, sump);
  // 2. rmsnorm(x) -> xn (bf16)
  rmsnorm_kernel<<<kT, 256, 0, stream>>>(x, attn_w, xn, nullptr);
  // 3. fused QKV GEMM (z selects wq/wk/wv)
  gemm_bt<<<dim3(kD / BN, kT / BM, 3), 256, 0, stream>>>(
      xn, kD, wq, wk, wv, 0, kD, qf, kf, vf, kD, 0, kT, kD, kD,
      nullptr, nullptr, nullptr, nullptr, nullptr);
  // 4. RoPE in-place on q,k
  rope_kernel<<<(kT * kNH * 32) / 256, 256, 0, stream>>>(qf, kf);
  // 5. causal attention -> attn_o (bf16)
  attn_kernel<<<dim3(kS / 64, kNH, kB), 256, 0, stream>>>(qf, kf, vf, attn_o);
  // 6. O-proj + residual(x) -> hbuf (fp32)
  gemm_bt<<<dim3(kD / BN, kT / BM, 1), 256, 0, stream>>>(
      attn_o, kD, wo, nullptr, nullptr, 0, kD, hbuf, nullptr, nullptr, kD, 0, kT, kD, kD,
      nullptr, nullptr, nullptr, nullptr, x);
  // 7. rmsnorm(h) -> hn (bf16) + rstd
  rmsnorm_kernel<<<kT, 256, 0, stream>>>(hbuf, ffn_w, hn, rstd);
  // 8. gate logits (fp32) + top2 + aux sums
  gate_kernel<<<kT, 64, 0, stream>>>(hbuf, ffn_w, rstd, gate_w, counts, sumg, sump, top_idx, top_gate);
  // 9. offsets/cursors + aux loss -> d_out[T*D]
  offsets_aux_kernel<<<1, 1, 0, stream>>>(counts, offs, cur, sumg, sump, out + (size_t)kT * kD);
  // 10. scatter assignments
  scatter_kernel<<<kSlots / 256, 256, 0, stream>>>(top_idx, top_gate, cur, assign_token, assign_gate, tok_slot);
  // 11. expert gate-proj and up-proj GEMMs (gathered rows of hn)
  gemm_bt<<<dim3(kHID / BN, kT / BM, kE), 256, 0, stream>>>(
      hn, kD, wg, nullptr, nullptr, (long)kHID * kD, kD, gbuf, nullptr, nullptr, kHID, 1, kT, kHID, kD,
      counts, offs, assign_token, nullptr, nullptr);
  gemm_bt<<<dim3(kHID / BN, kT / BM, kE), 256, 0, stream>>>(
      hn, kD, wu, nullptr, nullptr, (long)kHID * kD, kD, ubuf, nullptr, nullptr, kHID, 1, kT, kHID, kD,
      counts, offs, assign_token, nullptr, nullptr);
  // 12. silu(g)*u -> gbuf in place
  silu_mul_kernel<<<((size_t)kSlots * kHID / 8) / 256, 256, 0, stream>>>(gbuf, ubuf);
  // 13. down-proj GEMM, scaled by gate per row -> down (fp32)
  gemm_bt<<<dim3(kD / BN, kT / BM, kE), 256, 0, stream>>>(
      gbuf, kHID, wd, nullptr, nullptr, (long)kD * kHID, kHID, down, nullptr, nullptr, kD, 0, kT, kD, kHID,
      counts, offs, nullptr, assign_gate, nullptr);
  // 14. out = h + down[s0] + down[s1]
  final_kernel<<<kT, 256, 0, stream>>>(hbuf, down, tok_slot, out);
}

// Round 2
// 1139.861 us; speedup vs baseline: 1.2164x; 1.2164x over previous
//
#include <hip/hip_runtime.h>
#include <cstdint>

typedef __bf16 bf16;
typedef bf16 bf16x8 __attribute__((ext_vector_type(8)));
typedef bf16 bf16x4 __attribute__((ext_vector_type(4)));
typedef float f32x4 __attribute__((ext_vector_type(4)));

constexpr int kB = 2, kS = 1024, kD = 1024, kNH = 16, kHD = 64, kE = 8, kHID = 4096;
constexpr int kT = kB * kS;        // 2048 tokens
constexpr int kSlots = kT * 2;     // 4096 token-expert assignments (TOPK=2)
constexpr float kEPS = 1e-6f;

#define BM 128
#define BN 128
#define BK 32

// ---------------- RMSNorm: fp32 in -> bf16 out (+ optional rstd for gate) ----------------
__global__ __launch_bounds__(256) void rmsnorm_kernel(const float* __restrict__ x,
                                                      const float* __restrict__ w,
                                                      bf16* __restrict__ out,
                                                      float* __restrict__ rstd_out) {
  int t = blockIdx.x;
  int tid = threadIdx.x;
  const float4* xr = (const float4*)(x + (size_t)t * kD);
  float4 xv = xr[tid];
  float ss = xv.x * xv.x + xv.y * xv.y + xv.z * xv.z + xv.w * xv.w;
  for (int off = 32; off >= 1; off >>= 1) ss += __shfl_xor(ss, off, 64);
  __shared__ float red[4];
  int w64 = tid >> 6, lane = tid & 63;
  if (lane == 0) red[w64] = ss;
  __syncthreads();
  float tot = red[0] + red[1] + red[2] + red[3];
  float rstd = rsqrtf(tot / (float)kD + kEPS);
  const float4* wr = (const float4*)w;
  float4 wv = wr[tid];
  bf16* op = out + (size_t)t * kD + tid * 4;
  op[0] = (bf16)(xv.x * wv.x * rstd);
  op[1] = (bf16)(xv.y * wv.y * rstd);
  op[2] = (bf16)(xv.z * wv.z * rstd);
  op[3] = (bf16)(xv.w * wv.w * rstd);
  if (rstd_out && tid == 0) rstd_out[t] = rstd;
}

// ---------------- Generic NT GEMM: C[m,n] = sum_k A_bf16[m,k] * W_f32[n,k] ----------------
// Dense mode (counts==null): z in {0,1,2} selects (W0,C0)/(W1,C1)/(W2,C2), M=Mfix.
//   c_vt: when z==2, store C transposed per-head: Vt[(b*1024+col)*1024 + s].
// Expert mode (counts!=null): z = expert id; W = W0 + z*wstride; C = C0;
//   rows are [offsets[z], offsets[z]+counts[z]); A row via gather[] (or slot id).
__global__ __launch_bounds__(256) void gemm_bt(
    const bf16* __restrict__ A, int lda,
    const float* __restrict__ W0, const float* __restrict__ W1, const float* __restrict__ W2,
    long wstride, int ldw,
    void* __restrict__ C0, void* __restrict__ C1, void* __restrict__ C2,
    int ldc, int c_bf16, int c_vt,
    int Mfix, int N, int K,
    const int* __restrict__ counts, const int* __restrict__ offsets,
    const int* __restrict__ gather,
    const float* __restrict__ rowscale, const float* __restrict__ residual) {
  int z = blockIdx.z;
  const float* W = W0;
  void* C = C0;
  int cnt = Mfix, base = 0;
  if (counts) {
    cnt = counts[z];
    base = offsets[z];
    W = W0 + (long)z * wstride;
  } else {
    if (z == 1) { W = W1; C = C1; }
    else if (z == 2) { W = W2; C = C2; }
  }
  int vt = c_vt && (z == 2);
  int m0 = blockIdx.y * BM;
  if (m0 >= cnt) return;
  int n0 = blockIdx.x * BN;

  __shared__ __align__(16) bf16 As[BM * BK];
  __shared__ __align__(16) bf16 Ws[BN * BK];

  int tid = threadIdx.x;
  int sr = tid >> 1;            // 0..127
  int sc = (tid & 1) * 16;      // 0 or 16

  // resolve A row for staging
  int am = m0 + sr;
  int amc = (am < cnt) ? am : (cnt - 1);
  long arow;
  if (counts) {
    arow = gather ? (long)gather[base + amc] : (long)(base + amc);
  } else {
    arow = am;
  }
  const bf16* abase = A + arow * (long)lda + sc;
  const float* wbase = W + (long)(n0 + sr) * ldw + sc;

  int w = tid >> 6, lane = tid & 63;
  int wr = (w >> 1) * 64, wc = (w & 1) * 64;
  int r = lane & 15, q = lane >> 4;

  f32x4 acc[4][4];
#pragma unroll
  for (int i = 0; i < 4; ++i)
#pragma unroll
    for (int j = 0; j < 4; ++j) acc[i][j] = (f32x4){0.f, 0.f, 0.f, 0.f};

  for (int k0 = 0; k0 < K; k0 += BK) {
    // stage A (bf16 passthrough, 32B/thread)
    *(uint4*)&As[sr * BK + sc] = *(const uint4*)(abase + k0);
    *(uint4*)&As[sr * BK + sc + 8] = *(const uint4*)(abase + k0 + 8);
    // stage W (fp32 -> bf16 inline)
    const float4* wp = (const float4*)(wbase + k0);
    float4 f0 = wp[0], f1 = wp[1], f2 = wp[2], f3 = wp[3];
    bf16x8 w0, w1;
    w0[0] = (bf16)f0.x; w0[1] = (bf16)f0.y; w0[2] = (bf16)f0.z; w0[3] = (bf16)f0.w;
    w0[4] = (bf16)f1.x; w0[5] = (bf16)f1.y; w0[6] = (bf16)f1.z; w0[7] = (bf16)f1.w;
    w1[0] = (bf16)f2.x; w1[1] = (bf16)f2.y; w1[2] = (bf16)f2.z; w1[3] = (bf16)f2.w;
    w1[4] = (bf16)f3.x; w1[5] = (bf16)f3.y; w1[6] = (bf16)f3.z; w1[7] = (bf16)f3.w;
    *(bf16x8*)&Ws[sr * BK + sc] = w0;
    *(bf16x8*)&Ws[sr * BK + sc + 8] = w1;
    __syncthreads();

    bf16x8 af[4], bfr[4];
#pragma unroll
    for (int i = 0; i < 4; ++i) af[i] = *(const bf16x8*)&As[(wr + i * 16 + r) * BK + q * 8];
#pragma unroll
    for (int j = 0; j < 4; ++j) bfr[j] = *(const bf16x8*)&Ws[(wc + j * 16 + r) * BK + q * 8];
#pragma unroll
    for (int i = 0; i < 4; ++i)
#pragma unroll
      for (int j = 0; j < 4; ++j)
        acc[i][j] = __builtin_amdgcn_mfma_f32_16x16x32_bf16(af[i], bfr[j], acc[i][j], 0, 0, 0);
    __syncthreads();
  }

  // epilogue: C/D layout col=lane&15, row=quad*4+reg
#pragma unroll
  for (int i = 0; i < 4; ++i)
#pragma unroll
    for (int j = 0; j < 4; ++j) {
      int col = n0 + wc + j * 16 + r;
#pragma unroll
      for (int rg = 0; rg < 4; ++rg) {
        int m = m0 + wr + i * 16 + q * 4 + rg;
        if (m >= cnt) continue;
        long crow = base + m;
        float v = acc[i][j][rg];
        if (rowscale) v *= rowscale[crow];
        if (residual) v += residual[crow * (long)ldc + col];
        long cidx;
        if (vt) {
          // transposed per-head V store: [(b*1024 + h*64+d)][s]
          cidx = ((long)((crow >> 10) * 1024 + col) << 10) | (crow & 1023);
        } else {
          cidx = crow * (long)ldc + col;
        }
        if (c_bf16) ((bf16*)C)[cidx] = (bf16)v;
        else ((float*)C)[cidx] = v;
      }
    }
}

// ---------------- RoPE in-place on bf16 q,k ([t][h*64+d]) ----------------
__global__ __launch_bounds__(256) void rope_kernel(bf16* __restrict__ qb, bf16* __restrict__ kb) {
  int id = blockIdx.x * 256 + threadIdx.x;  // kT*kNH*32 threads
  int j = id & 31;
  int h = (id >> 5) & (kNH - 1);
  int t = id >> 9;
  int s = t & (kS - 1);
  float inv = expf(-9.210340371976184f * (float)j * (1.0f / 32.0f));
  float fr = (float)s * inv;
  float c = cosf(fr), sn = sinf(fr);
  size_t idx = (size_t)t * kD + h * kHD + j;
  float x1 = (float)qb[idx], x2 = (float)qb[idx + 32];
  qb[idx] = (bf16)(x1 * c - x2 * sn);
  qb[idx + 32] = (bf16)(x2 * c + x1 * sn);
  float y1 = (float)kb[idx], y2 = (float)kb[idx + 32];
  kb[idx] = (bf16)(y1 * c - y2 * sn);
  kb[idx + 32] = (bf16)(y2 * c + y1 * sn);
}

// ---------------- MFMA causal flash attention ----------------
// grid (S/64, NH, B), 256 thr = 4 waves; wave w owns q rows w*16..w*16+15.
// S = Q K^T via mfma(A=Q,B=K); softmax rows in C-layout (row=quad*4+reg);
// P staged per-wave in LDS row-major (stride 72); PV computes O^T via
// mfma(A=V^T, B=P) so both fragments are contiguous b128 reads.
__global__ __launch_bounds__(256) void attn_mfma_kernel(const bf16* __restrict__ qb,
                                                        const bf16* __restrict__ kb,
                                                        const bf16* __restrict__ vt,
                                                        bf16* __restrict__ o) {
  int qt = gridDim.x - 1 - blockIdx.x;  // heavy tiles first
  int h = blockIdx.y, b = blockIdx.z;
  __shared__ __align__(16) bf16 Ks[64 * 72];
  __shared__ __align__(16) bf16 Vs[64 * 72];   // V^T tile: [d][key]
  __shared__ __align__(16) bf16 Pw[4 * 16 * 72];
  int tid = threadIdx.x, w = tid >> 6, lane = tid & 63;
  int l = lane & 15, quad = lane >> 4;

  // preload Q A-fragments (A[m=l][k=quad*8+j]), two 32-deep d chunks
  const bf16* qptr = qb + ((size_t)(b * kS + qt * 64 + w * 16 + l)) * kD + h * kHD + quad * 8;
  bf16x8 aq0 = *(const bf16x8*)qptr;
  bf16x8 aq1 = *(const bf16x8*)(qptr + 32);

  f32x4 oacc[4];
#pragma unroll
  for (int mt = 0; mt < 4; ++mt) oacc[mt] = (f32x4){0.f, 0.f, 0.f, 0.f};
  float mrun[4], lrun[4];
#pragma unroll
  for (int rr = 0; rr < 4; ++rr) { mrun[rr] = -1e30f; lrun[rr] = 0.f; }

  int skey = tid >> 2, sdg = (tid & 3) * 16;    // K staging: row=key, 16 d per thread
  int svd = tid >> 2, svk = (tid & 3) * 16;     // V staging: row=d, 16 keys per thread
  const bf16* kbase = kb + ((size_t)(b * kS + skey)) * kD + h * kHD + sdg;
  const bf16* vbase = vt + ((size_t)(b * 1024 + h * kHD + svd)) * kS + svk;
  bf16* pmy = Pw + w * (16 * 72);
  int srcl = (l >> 2) << 4;  // lane holding state for q=l (its quad = l>>2)
  int rsel = l & 3;

  for (int kt = 0; kt <= qt; ++kt) {
    __syncthreads();
    // stage K tile [key][d] and V^T tile [d][key]
    const bf16* ks = kbase + (size_t)kt * 64 * kD;
    *(bf16x8*)&Ks[skey * 72 + sdg] = *(const bf16x8*)ks;
    *(bf16x8*)&Ks[skey * 72 + sdg + 8] = *(const bf16x8*)(ks + 8);
    const bf16* vs = vbase + kt * 64;
    *(bf16x8*)&Vs[svd * 72 + svk] = *(const bf16x8*)vs;
    *(bf16x8*)&Vs[svd * 72 + svk + 8] = *(const bf16x8*)(vs + 8);
    __syncthreads();

    // QK^T: 4 col-tiles (16 keys each) x 2 d-chunks
    f32x4 sc[4];
#pragma unroll
    for (int jt = 0; jt < 4; ++jt) {
      bf16x8 bk0 = *(const bf16x8*)&Ks[(jt * 16 + l) * 72 + quad * 8];
      bf16x8 bk1 = *(const bf16x8*)&Ks[(jt * 16 + l) * 72 + 32 + quad * 8];
      f32x4 zz = (f32x4){0.f, 0.f, 0.f, 0.f};
      zz = __builtin_amdgcn_mfma_f32_16x16x32_bf16(aq0, bk0, zz, 0, 0, 0);
      zz = __builtin_amdgcn_mfma_f32_16x16x32_bf16(aq1, bk1, zz, 0, 0, 0);
      sc[jt] = zz;
    }
    // scale + causal mask (diagonal tile only)
    int diag = (kt == qt);
    int qrow = w * 16 + quad * 4;
#pragma unroll
    for (int jt = 0; jt < 4; ++jt)
#pragma unroll
      for (int rr = 0; rr < 4; ++rr) {
        float v = sc[jt][rr] * 0.125f;
        if (diag && (jt * 16 + l > qrow + rr)) v = -1e30f;
        sc[jt][rr] = v;
      }
    // row max across 16 cols (lanes sharing quad)
    float mt_[4];
#pragma unroll
    for (int rr = 0; rr < 4; ++rr) {
      float m = fmaxf(fmaxf(sc[0][rr], sc[1][rr]), fmaxf(sc[2][rr], sc[3][rr]));
      m = fmaxf(m, __shfl_xor(m, 1, 64));
      m = fmaxf(m, __shfl_xor(m, 2, 64));
      m = fmaxf(m, __shfl_xor(m, 4, 64));
      m = fmaxf(m, __shfl_xor(m, 8, 64));
      mt_[rr] = m;
    }
    float alpha[4];
#pragma unroll
    for (int rr = 0; rr < 4; ++rr) {
      float mn = fmaxf(mrun[rr], mt_[rr]);
      alpha[rr] = __expf(mrun[rr] - mn);
      mrun[rr] = mn;
    }
#pragma unroll
    for (int jt = 0; jt < 4; ++jt)
#pragma unroll
      for (int rr = 0; rr < 4; ++rr) sc[jt][rr] = __expf(sc[jt][rr] - mrun[rr]);
    float rs[4];
#pragma unroll
    for (int rr = 0; rr < 4; ++rr) {
      float s = sc[0][rr] + sc[1][rr] + sc[2][rr] + sc[3][rr];
      s += __shfl_xor(s, 1, 64);
      s += __shfl_xor(s, 2, 64);
      s += __shfl_xor(s, 4, 64);
      s += __shfl_xor(s, 8, 64);
      rs[rr] = s;
      lrun[rr] = lrun[rr] * alpha[rr] + s;
    }
    // write P (bf16) to per-wave LDS, row-major [q_local][key]
#pragma unroll
    for (int jt = 0; jt < 4; ++jt)
#pragma unroll
      for (int rr = 0; rr < 4; ++rr)
        pmy[(quad * 4 + rr) * 72 + jt * 16 + l] = (bf16)sc[jt][rr];
    // alpha for this lane's O^T column q = l
    float a0 = __shfl(alpha[0], srcl, 64), a1 = __shfl(alpha[1], srcl, 64);
    float a2 = __shfl(alpha[2], srcl, 64), a3 = __shfl(alpha[3], srcl, 64);
    float aq = (rsel == 0) ? a0 : (rsel == 1) ? a1 : (rsel == 2) ? a2 : a3;
#pragma unroll
    for (int mt = 0; mt < 4; ++mt) {
      oacc[mt][0] *= aq; oacc[mt][1] *= aq; oacc[mt][2] *= aq; oacc[mt][3] *= aq;
    }
    // PV: O^T[d][q] += Vt(A) . P(B)
    bf16x8 bp0 = *(const bf16x8*)&pmy[l * 72 + quad * 8];
    bf16x8 bp1 = *(const bf16x8*)&pmy[l * 72 + 32 + quad * 8];
#pragma unroll
    for (int mt = 0; mt < 4; ++mt) {
      bf16x8 av0 = *(const bf16x8*)&Vs[(mt * 16 + l) * 72 + quad * 8];
      bf16x8 av1 = *(const bf16x8*)&Vs[(mt * 16 + l) * 72 + 32 + quad * 8];
      oacc[mt] = __builtin_amdgcn_mfma_f32_16x16x32_bf16(av0, bp0, oacc[mt], 0, 0, 0);
      oacc[mt] = __builtin_amdgcn_mfma_f32_16x16x32_bf16(av1, bp1, oacc[mt], 0, 0, 0);
    }
  }

  // epilogue: l_inv for q=l, store O^T -> o[token][d]
  float l0 = __shfl(lrun[0], srcl, 64), l1 = __shfl(lrun[1], srcl, 64);
  float l2 = __shfl(lrun[2], srcl, 64), l3 = __shfl(lrun[3], srcl, 64);
  float lq = (rsel == 0) ? l0 : (rsel == 1) ? l1 : (rsel == 2) ? l2 : l3;
  float linv = 1.f / lq;
  bf16* obase = o + ((size_t)(b * kS + qt * 64 + w * 16 + l)) * kD + h * kHD + quad * 4;
#pragma unroll
  for (int mt = 0; mt < 4; ++mt) {
    bf16x4 ov;
#pragma unroll
    for (int rr = 0; rr < 4; ++rr) ov[rr] = (bf16)(oacc[mt][rr] * linv);
    *(bf16x4*)(obase + mt * 16) = ov;
  }
}

// ---------------- zero the small counters ----------------
__global__ void zero_kernel(int* counts, float* sumg, float* sump) {
  int i = threadIdx.x;
  if (i < kE) { counts[i] = 0; sumg[i] = 0.f; sump[i] = 0.f; }
}

// ---------------- Gate: fp32 logits from h (pre-norm) * ffn_w * rstd; top-2 ----------------
__global__ __launch_bounds__(64) void gate_kernel(const float* __restrict__ h,
                                                  const float* __restrict__ ffnw,
                                                  const float* __restrict__ rstd,
                                                  const float* __restrict__ gw,
                                                  int* __restrict__ counts,
                                                  float* __restrict__ sumg, float* __restrict__ sump,
                                                  int* __restrict__ top_idx, float* __restrict__ top_gate) {
  int t = blockIdx.x;
  int lane = threadIdx.x;
  int e = lane >> 3, c = lane & 7;
  const float4* hp = (const float4*)(h + (size_t)t * kD + c * 128);
  const float4* wp = (const float4*)(ffnw + c * 128);
  const float4* gp = (const float4*)(gw + (size_t)e * kD + c * 128);
  float sum = 0.f;
#pragma unroll 8
  for (int i = 0; i < 32; ++i) {
    float4 a = hp[i], b = wp[i], g4 = gp[i];
    sum += a.x * b.x * g4.x + a.y * b.y * g4.y + a.z * b.z * g4.z + a.w * b.w * g4.w;
  }
  sum += __shfl_xor(sum, 1, 64);
  sum += __shfl_xor(sum, 2, 64);
  sum += __shfl_xor(sum, 4, 64);
  __shared__ float lg[kE];
  if (c == 0) lg[e] = sum * rstd[t];
  __syncthreads();
  if (lane == 0) {
    float l[kE];
#pragma unroll
    for (int i = 0; i < kE; ++i) l[i] = lg[i];
    int i1 = 0;
#pragma unroll
    for (int i = 1; i < kE; ++i) if (l[i] > l[i1]) i1 = i;
    int i2 = (i1 == 0) ? 1 : 0;
#pragma unroll
    for (int i = 0; i < kE; ++i) if (i != i1 && l[i] > l[i2]) i2 = i;
    float e2 = __expf(l[i2] - l[i1]);
    float g1 = 1.f / (1.f + e2);
    float g2 = e2 / (1.f + e2);
    float pm = l[i1];
    float pr[kE], ps = 0.f;
#pragma unroll
    for (int i = 0; i < kE; ++i) { pr[i] = __expf(l[i] - pm); ps += pr[i]; }
    float pinv = 1.f / ps;
#pragma unroll
    for (int i = 0; i < kE; ++i) atomicAdd(&sump[i], pr[i] * pinv);
    atomicAdd(&sumg[i1], g1);
    atomicAdd(&sumg[i2], g2);
    atomicAdd(&counts[i1], 1);
    atomicAdd(&counts[i2], 1);
    top_idx[2 * t] = i1; top_idx[2 * t + 1] = i2;
    top_gate[2 * t] = g1; top_gate[2 * t + 1] = g2;
  }
}

// ---------------- offsets + cursors + aux loss ----------------
__global__ void offsets_aux_kernel(const int* counts, int* offs, int* cur,
                                   const float* sumg, const float* sump, float* out_aux) {
  if (threadIdx.x == 0 && blockIdx.x == 0) {
    int acc = 0;
    for (int e = 0; e < kE; ++e) { offs[e] = acc; cur[e] = acc; acc += counts[e]; }
    float aux = 0.f;
    for (int e = 0; e < kE; ++e) aux += (sumg[e] / (float)kT) * (sump[e] / (float)kT);
    out_aux[0] = (float)kE * aux;
  }
}

// ---------------- scatter token->slot ----------------
__global__ __launch_bounds__(256) void scatter_kernel(const int* __restrict__ top_idx,
                                                      const float* __restrict__ top_gate,
                                                      int* __restrict__ cur,
                                                      int* __restrict__ assign_token,
                                                      float* __restrict__ assign_gate,
                                                      int* __restrict__ tok_slot) {
  int id = blockIdx.x * 256 + threadIdx.x;
  if (id >= kSlots) return;
  int e = top_idx[id];
  int slot = atomicAdd(&cur[e], 1);
  assign_token[slot] = id >> 1;
  assign_gate[slot] = top_gate[id];
  tok_slot[id] = slot;
}

// ---------------- silu(g)*u elementwise, in-place into g ----------------
__global__ __launch_bounds__(256) void silu_mul_kernel(bf16* __restrict__ gbuf, const bf16* __restrict__ ubuf) {
  size_t id = ((size_t)blockIdx.x * 256 + threadIdx.x) * 8;
  bf16x8 gv = *(bf16x8*)(gbuf + id);
  bf16x8 uv = *(const bf16x8*)(ubuf + id);
  bf16x8 ov;
#pragma unroll
  for (int i = 0; i < 8; ++i) {
    float gf = (float)gv[i], uf = (float)uv[i];
    float sig = 1.f / (1.f + __expf(-gf));
    ov[i] = (bf16)(gf * sig * uf);
  }
  *(bf16x8*)(gbuf + id) = ov;
}

// ---------------- final: out = h + down[slot0] + down[slot1] (gates pre-applied) ----------------
__global__ __launch_bounds__(256) void final_kernel(const float* __restrict__ h,
                                                    const float* __restrict__ down,
                                                    const int* __restrict__ tok_slot,
                                                    float* __restrict__ out) {
  int t = blockIdx.x, tid = threadIdx.x;
  int s0 = tok_slot[2 * t], s1 = tok_slot[2 * t + 1];
  const float4* hp = (const float4*)(h + (size_t)t * kD);
  const float4* d0 = (const float4*)(down + (size_t)s0 * kD);
  const float4* d1 = (const float4*)(down + (size_t)s1 * kD);
  float4 a = hp[tid], b0 = d0[tid], b1 = d1[tid];
  float4 rv;
  rv.x = a.x + b0.x + b1.x;
  rv.y = a.y + b0.y + b1.y;
  rv.z = a.z + b0.z + b1.z;
  rv.w = a.w + b0.w + b1.w;
  ((float4*)(out + (size_t)t * kD))[tid] = rv;
}

extern "C" void kernel_launch(void* const* d_in, const int* in_sizes, int n_in,
                              void* d_out, int out_size, void* d_ws, size_t ws_size,
                              hipStream_t stream) {
  const float* x = (const float*)d_in[0];
  const float* wq = (const float*)d_in[1];
  const float* wk = (const float*)d_in[2];
  const float* wv = (const float*)d_in[3];
  const float* wo = (const float*)d_in[4];
  const float* attn_w = (const float*)d_in[5];
  const float* ffn_w = (const float*)d_in[6];
  const float* gate_w = (const float*)d_in[7];
  const float* wg = (const float*)d_in[8];
  const float* wu = (const float*)d_in[9];
  const float* wd = (const float*)d_in[10];
  float* out = (float*)d_out;

  char* ws = (char*)d_ws;
  size_t off = 0;
  auto alloc = [&](size_t bytes) -> void* {
    void* p = ws + off;
    off = (off + bytes + 255) & ~(size_t)255;
    return p;
  };
  bf16* xn = (bf16*)alloc((size_t)kT * kD * 2);
  bf16* qb = (bf16*)alloc((size_t)kT * kD * 2);
  bf16* kb = (bf16*)alloc((size_t)kT * kD * 2);
  bf16* vtb = (bf16*)alloc((size_t)kT * kD * 2);  // V^T: [(b*1024+h*64+d)][s]
  bf16* attn_o = (bf16*)alloc((size_t)kT * kD * 2);
  float* hbuf = (float*)alloc((size_t)kT * kD * 4);
  bf16* hn = (bf16*)alloc((size_t)kT * kD * 2);
  float* rstd = (float*)alloc((size_t)kT * 4);
  int* counts = (int*)alloc(kE * 4);
  int* cur = (int*)alloc(kE * 4);
  int* offs = (int*)alloc(kE * 4);
  float* sumg = (float*)alloc(kE * 4);
  float* sump = (float*)alloc(kE * 4);
  int* top_idx = (int*)alloc((size_t)kSlots * 4);
  float* top_gate = (float*)alloc((size_t)kSlots * 4);
  int* assign_token = (int*)alloc((size_t)kSlots * 4);
  float* assign_gate = (float*)alloc((size_t)kSlots * 4);
  int* tok_slot = (int*)alloc((size_t)kSlots * 4);
  bf16* gbuf = (bf16*)alloc((size_t)kSlots * kHID * 2);
  bf16* ubuf = (bf16*)alloc((size_t)kSlots * kHID * 2);
  float* down = (float*)alloc((size_t)kSlots * kD * 4);
  (void)ws_size; (void)n_in; (void)in_sizes; (void)out_size;

  // 1. zero counters
  zero_kernel<<<1, 64, 0, stream>>>(counts, sumg, sump);
  // 2. rmsnorm(x) -> xn (bf16)
  rmsnorm_kernel<<<kT, 256, 0, stream>>>(x, attn_w, xn, nullptr);
  // 3. fused QKV GEMM -> qb, kb (bf16) and V^T (bf16, transposed store)
  gemm_bt<<<dim3(kD / BN, kT / BM, 3), 256, 0, stream>>>(
      xn, kD, wq, wk, wv, 0, kD, qb, kb, vtb, kD, 1, 1, kT, kD, kD,
      nullptr, nullptr, nullptr, nullptr, nullptr);
  // 4. RoPE in-place on q,k (bf16)
  rope_kernel<<<(kT * kNH * 32) / 256, 256, 0, stream>>>(qb, kb);
  // 5. MFMA causal flash attention -> attn_o (bf16)
  attn_mfma_kernel<<<dim3(kS / 64, kNH, kB), 256, 0, stream>>>(qb, kb, vtb, attn_o);
  // 6. O-proj + residual(x) -> hbuf (fp32)
  gemm_bt<<<dim3(kD / BN, kT / BM, 1), 256, 0, stream>>>(
      attn_o, kD, wo, nullptr, nullptr, 0, kD, hbuf, nullptr, nullptr, kD, 0, 0, kT, kD, kD,
      nullptr, nullptr, nullptr, nullptr, x);
  // 7. rmsnorm(h) -> hn (bf16) + rstd
  rmsnorm_kernel<<<kT, 256, 0, stream>>>(hbuf, ffn_w, hn, rstd);
  // 8. gate logits (fp32) + top2 + aux sums
  gate_kernel<<<kT, 64, 0, stream>>>(hbuf, ffn_w, rstd, gate_w, counts, sumg, sump, top_idx, top_gate);
  // 9. offsets/cursors + aux loss -> d_out[T*D]
  offsets_aux_kernel<<<1, 1, 0, stream>>>(counts, offs, cur, sumg, sump, out + (size_t)kT * kD);
  // 10. scatter assignments
  scatter_kernel<<<kSlots / 256, 256, 0, stream>>>(top_idx, top_gate, cur, assign_token, assign_gate, tok_slot);
  // 11. expert gate-proj and up-proj GEMMs (gathered rows of hn)
  gemm_bt<<<dim3(kHID / BN, kT / BM, kE), 256, 0, stream>>>(
      hn, kD, wg, nullptr, nullptr, (long)kHID * kD, kD, gbuf, nullptr, nullptr, kHID, 1, 0, kT, kHID, kD,
      counts, offs, assign_token, nullptr, nullptr);
  gemm_bt<<<dim3(kHID / BN, kT / BM, kE), 256, 0, stream>>>(
      hn, kD, wu, nullptr, nullptr, (long)kHID * kD, kD, ubuf, nullptr, nullptr, kHID, 1, 0, kT, kHID, kD,
      counts, offs, assign_token, nullptr, nullptr);
  // 12. silu(g)*u -> gbuf in place
  silu_mul_kernel<<<((size_t)kSlots * kHID / 8) / 256, 256, 0, stream>>>(gbuf, ubuf);
  // 13. down-proj GEMM, scaled by gate per row -> down (fp32)
  gemm_bt<<<dim3(kD / BN, kT / BM, kE), 256, 0, stream>>>(
      gbuf, kHID, wd, nullptr, nullptr, (long)kD * kHID, kHID, down, nullptr, nullptr, kD, 0, 0, kT, kD, kHID,
      counts, offs, nullptr, assign_gate, nullptr);
  // 14. out = h + down[s0] + down[s1]
  final_kernel<<<kT, 256, 0, stream>>>(hbuf, down, tok_slot, out);
}

// Round 3
// 933.896 us; speedup vs baseline: 1.4847x; 1.2205x over previous
//
#include <hip/hip_runtime.h>
#include <cstdint>

typedef __bf16 bf16;
typedef bf16 bf16x8 __attribute__((ext_vector_type(8)));
typedef bf16 bf16x4 __attribute__((ext_vector_type(4)));
typedef float f32x4 __attribute__((ext_vector_type(4)));

constexpr int kB = 2, kS = 1024, kD = 1024, kNH = 16, kHD = 64, kE = 8, kHID = 4096;
constexpr int kT = kB * kS;        // 2048 tokens
constexpr int kSlots = kT * 2;     // 4096 token-expert assignments (TOPK=2)
constexpr float kEPS = 1e-6f;

#define BM 128
#define BN 128
#define BK 32

// ---------------- RMSNorm: fp32 in -> bf16 out (+ optional rstd for gate) ----------------
__global__ __launch_bounds__(256) void rmsnorm_kernel(const float* __restrict__ x,
                                                      const float* __restrict__ w,
                                                      bf16* __restrict__ out,
                                                      float* __restrict__ rstd_out) {
  int t = blockIdx.x;
  int tid = threadIdx.x;
  const float4* xr = (const float4*)(x + (size_t)t * kD);
  float4 xv = xr[tid];
  float ss = xv.x * xv.x + xv.y * xv.y + xv.z * xv.z + xv.w * xv.w;
  for (int off = 32; off >= 1; off >>= 1) ss += __shfl_xor(ss, off, 64);
  __shared__ float red[4];
  int w64 = tid >> 6, lane = tid & 63;
  if (lane == 0) red[w64] = ss;
  __syncthreads();
  float tot = red[0] + red[1] + red[2] + red[3];
  float rstd = rsqrtf(tot / (float)kD + kEPS);
  const float4* wr = (const float4*)w;
  float4 wv = wr[tid];
  bf16* op = out + (size_t)t * kD + tid * 4;
  op[0] = (bf16)(xv.x * wv.x * rstd);
  op[1] = (bf16)(xv.y * wv.y * rstd);
  op[2] = (bf16)(xv.z * wv.z * rstd);
  op[3] = (bf16)(xv.w * wv.w * rstd);
  if (rstd_out && tid == 0) rstd_out[t] = rstd;
}

// ---------------- Generic NT GEMM: C[m,n] = sum_k A_bf16[m,k] * W_f32[n,k] ----------------
__global__ __launch_bounds__(256) void gemm_bt(
    const bf16* __restrict__ A, int lda,
    const float* __restrict__ W0, const float* __restrict__ W1, const float* __restrict__ W2,
    long wstride, int ldw,
    void* __restrict__ C0, void* __restrict__ C1, void* __restrict__ C2,
    int ldc, int c_bf16, int c_vt,
    int Mfix, int N, int K,
    const int* __restrict__ counts, const int* __restrict__ offsets,
    const int* __restrict__ gather,
    const float* __restrict__ rowscale, const float* __restrict__ residual) {
  int z = blockIdx.z;
  const float* W = W0;
  void* C = C0;
  int cnt = Mfix, base = 0;
  if (counts) {
    cnt = counts[z];
    base = offsets[z];
    W = W0 + (long)z * wstride;
  } else {
    if (z == 1) { W = W1; C = C1; }
    else if (z == 2) { W = W2; C = C2; }
  }
  int vt = c_vt && (z == 2);
  int m0 = blockIdx.y * BM;
  if (m0 >= cnt) return;
  int n0 = blockIdx.x * BN;

  __shared__ __align__(16) bf16 As[BM * BK];
  __shared__ __align__(16) bf16 Ws[BN * BK];

  int tid = threadIdx.x;
  int sr = tid >> 1;            // 0..127
  int sc = (tid & 1) * 16;      // 0 or 16

  int am = m0 + sr;
  int amc = (am < cnt) ? am : (cnt - 1);
  long arow;
  if (counts) {
    arow = gather ? (long)gather[base + amc] : (long)(base + amc);
  } else {
    arow = am;
  }
  const bf16* abase = A + arow * (long)lda + sc;
  const float* wbase = W + (long)(n0 + sr) * ldw + sc;

  int w = tid >> 6, lane = tid & 63;
  int wr = (w >> 1) * 64, wc = (w & 1) * 64;
  int r = lane & 15, q = lane >> 4;

  f32x4 acc[4][4];
#pragma unroll
  for (int i = 0; i < 4; ++i)
#pragma unroll
    for (int j = 0; j < 4; ++j) acc[i][j] = (f32x4){0.f, 0.f, 0.f, 0.f};

  for (int k0 = 0; k0 < K; k0 += BK) {
    *(uint4*)&As[sr * BK + sc] = *(const uint4*)(abase + k0);
    *(uint4*)&As[sr * BK + sc + 8] = *(const uint4*)(abase + k0 + 8);
    const float4* wp = (const float4*)(wbase + k0);
    float4 f0 = wp[0], f1 = wp[1], f2 = wp[2], f3 = wp[3];
    bf16x8 w0, w1;
    w0[0] = (bf16)f0.x; w0[1] = (bf16)f0.y; w0[2] = (bf16)f0.z; w0[3] = (bf16)f0.w;
    w0[4] = (bf16)f1.x; w0[5] = (bf16)f1.y; w0[6] = (bf16)f1.z; w0[7] = (bf16)f1.w;
    w1[0] = (bf16)f2.x; w1[1] = (bf16)f2.y; w1[2] = (bf16)f2.z; w1[3] = (bf16)f2.w;
    w1[4] = (bf16)f3.x; w1[5] = (bf16)f3.y; w1[6] = (bf16)f3.z; w1[7] = (bf16)f3.w;
    *(bf16x8*)&Ws[sr * BK + sc] = w0;
    *(bf16x8*)&Ws[sr * BK + sc + 8] = w1;
    __syncthreads();

    bf16x8 af[4], bfr[4];
#pragma unroll
    for (int i = 0; i < 4; ++i) af[i] = *(const bf16x8*)&As[(wr + i * 16 + r) * BK + q * 8];
#pragma unroll
    for (int j = 0; j < 4; ++j) bfr[j] = *(const bf16x8*)&Ws[(wc + j * 16 + r) * BK + q * 8];
#pragma unroll
    for (int i = 0; i < 4; ++i)
#pragma unroll
      for (int j = 0; j < 4; ++j)
        acc[i][j] = __builtin_amdgcn_mfma_f32_16x16x32_bf16(af[i], bfr[j], acc[i][j], 0, 0, 0);
    __syncthreads();
  }

#pragma unroll
  for (int i = 0; i < 4; ++i)
#pragma unroll
    for (int j = 0; j < 4; ++j) {
      int col = n0 + wc + j * 16 + r;
#pragma unroll
      for (int rg = 0; rg < 4; ++rg) {
        int m = m0 + wr + i * 16 + q * 4 + rg;
        if (m >= cnt) continue;
        long crow = base + m;
        float v = acc[i][j][rg];
        if (rowscale) v *= rowscale[crow];
        if (residual) v += residual[crow * (long)ldc + col];
        long cidx;
        if (vt) {
          cidx = ((long)((crow >> 10) * 1024 + col) << 10) | (crow & 1023);
        } else {
          cidx = crow * (long)ldc + col;
        }
        if (c_bf16) ((bf16*)C)[cidx] = (bf16)v;
        else ((float*)C)[cidx] = v;
      }
    }
}

// ---------------- RoPE in-place on bf16 q,k ([t][h*64+d]) ----------------
__global__ __launch_bounds__(256) void rope_kernel(bf16* __restrict__ qb, bf16* __restrict__ kb) {
  int id = blockIdx.x * 256 + threadIdx.x;  // kT*kNH*32 threads
  int j = id & 31;
  int h = (id >> 5) & (kNH - 1);
  int t = id >> 9;
  int s = t & (kS - 1);
  float inv = expf(-9.210340371976184f * (float)j * (1.0f / 32.0f));
  float fr = (float)s * inv;
  float c = cosf(fr), sn = sinf(fr);
  size_t idx = (size_t)t * kD + h * kHD + j;
  float x1 = (float)qb[idx], x2 = (float)qb[idx + 32];
  qb[idx] = (bf16)(x1 * c - x2 * sn);
  qb[idx + 32] = (bf16)(x2 * c + x1 * sn);
  float y1 = (float)kb[idx], y2 = (float)kb[idx + 32];
  kb[idx] = (bf16)(y1 * c - y2 * sn);
  kb[idx + 32] = (bf16)(y2 * c + y1 * sn);
}

// ---------------- MFMA causal flash attention ----------------
__global__ __launch_bounds__(256) void attn_mfma_kernel(const bf16* __restrict__ qb,
                                                        const bf16* __restrict__ kb,
                                                        const bf16* __restrict__ vt,
                                                        bf16* __restrict__ o) {
  int qt = gridDim.x - 1 - blockIdx.x;  // heavy tiles first
  int h = blockIdx.y, b = blockIdx.z;
  __shared__ __align__(16) bf16 Ks[64 * 72];
  __shared__ __align__(16) bf16 Vs[64 * 72];   // V^T tile: [d][key]
  __shared__ __align__(16) bf16 Pw[4 * 16 * 72];
  int tid = threadIdx.x, w = tid >> 6, lane = tid & 63;
  int l = lane & 15, quad = lane >> 4;

  const bf16* qptr = qb + ((size_t)(b * kS + qt * 64 + w * 16 + l)) * kD + h * kHD + quad * 8;
  bf16x8 aq0 = *(const bf16x8*)qptr;
  bf16x8 aq1 = *(const bf16x8*)(qptr + 32);

  f32x4 oacc[4];
#pragma unroll
  for (int mt = 0; mt < 4; ++mt) oacc[mt] = (f32x4){0.f, 0.f, 0.f, 0.f};
  float mrun[4], lrun[4];
#pragma unroll
  for (int rr = 0; rr < 4; ++rr) { mrun[rr] = -1e30f; lrun[rr] = 0.f; }

  int skey = tid >> 2, sdg = (tid & 3) * 16;
  int svd = tid >> 2, svk = (tid & 3) * 16;
  const bf16* kbase = kb + ((size_t)(b * kS + skey)) * kD + h * kHD + sdg;
  const bf16* vbase = vt + ((size_t)(b * 1024 + h * kHD + svd)) * kS + svk;
  bf16* pmy = Pw + w * (16 * 72);
  int srcl = (l >> 2) << 4;
  int rsel = l & 3;

  for (int kt = 0; kt <= qt; ++kt) {
    __syncthreads();
    const bf16* ks = kbase + (size_t)kt * 64 * kD;
    *(bf16x8*)&Ks[skey * 72 + sdg] = *(const bf16x8*)ks;
    *(bf16x8*)&Ks[skey * 72 + sdg + 8] = *(const bf16x8*)(ks + 8);
    const bf16* vs = vbase + kt * 64;
    *(bf16x8*)&Vs[svd * 72 + svk] = *(const bf16x8*)vs;
    *(bf16x8*)&Vs[svd * 72 + svk + 8] = *(const bf16x8*)(vs + 8);
    __syncthreads();

    f32x4 sc[4];
#pragma unroll
    for (int jt = 0; jt < 4; ++jt) {
      bf16x8 bk0 = *(const bf16x8*)&Ks[(jt * 16 + l) * 72 + quad * 8];
      bf16x8 bk1 = *(const bf16x8*)&Ks[(jt * 16 + l) * 72 + 32 + quad * 8];
      f32x4 zz = (f32x4){0.f, 0.f, 0.f, 0.f};
      zz = __builtin_amdgcn_mfma_f32_16x16x32_bf16(aq0, bk0, zz, 0, 0, 0);
      zz = __builtin_amdgcn_mfma_f32_16x16x32_bf16(aq1, bk1, zz, 0, 0, 0);
      sc[jt] = zz;
    }
    int diag = (kt == qt);
    int qrow = w * 16 + quad * 4;
#pragma unroll
    for (int jt = 0; jt < 4; ++jt)
#pragma unroll
      for (int rr = 0; rr < 4; ++rr) {
        float v = sc[jt][rr] * 0.125f;
        if (diag && (jt * 16 + l > qrow + rr)) v = -1e30f;
        sc[jt][rr] = v;
      }
    float mt_[4];
#pragma unroll
    for (int rr = 0; rr < 4; ++rr) {
      float m = fmaxf(fmaxf(sc[0][rr], sc[1][rr]), fmaxf(sc[2][rr], sc[3][rr]));
      m = fmaxf(m, __shfl_xor(m, 1, 64));
      m = fmaxf(m, __shfl_xor(m, 2, 64));
      m = fmaxf(m, __shfl_xor(m, 4, 64));
      m = fmaxf(m, __shfl_xor(m, 8, 64));
      mt_[rr] = m;
    }
    float alpha[4];
#pragma unroll
    for (int rr = 0; rr < 4; ++rr) {
      float mn = fmaxf(mrun[rr], mt_[rr]);
      alpha[rr] = __expf(mrun[rr] - mn);
      mrun[rr] = mn;
    }
#pragma unroll
    for (int jt = 0; jt < 4; ++jt)
#pragma unroll
      for (int rr = 0; rr < 4; ++rr) sc[jt][rr] = __expf(sc[jt][rr] - mrun[rr]);
#pragma unroll
    for (int rr = 0; rr < 4; ++rr) {
      float s = sc[0][rr] + sc[1][rr] + sc[2][rr] + sc[3][rr];
      s += __shfl_xor(s, 1, 64);
      s += __shfl_xor(s, 2, 64);
      s += __shfl_xor(s, 4, 64);
      s += __shfl_xor(s, 8, 64);
      lrun[rr] = lrun[rr] * alpha[rr] + s;
    }
#pragma unroll
    for (int jt = 0; jt < 4; ++jt)
#pragma unroll
      for (int rr = 0; rr < 4; ++rr)
        pmy[(quad * 4 + rr) * 72 + jt * 16 + l] = (bf16)sc[jt][rr];
    float a0 = __shfl(alpha[0], srcl, 64), a1 = __shfl(alpha[1], srcl, 64);
    float a2 = __shfl(alpha[2], srcl, 64), a3 = __shfl(alpha[3], srcl, 64);
    float aq = (rsel == 0) ? a0 : (rsel == 1) ? a1 : (rsel == 2) ? a2 : a3;
#pragma unroll
    for (int mt = 0; mt < 4; ++mt) {
      oacc[mt][0] *= aq; oacc[mt][1] *= aq; oacc[mt][2] *= aq; oacc[mt][3] *= aq;
    }
    bf16x8 bp0 = *(const bf16x8*)&pmy[l * 72 + quad * 8];
    bf16x8 bp1 = *(const bf16x8*)&pmy[l * 72 + 32 + quad * 8];
#pragma unroll
    for (int mt = 0; mt < 4; ++mt) {
      bf16x8 av0 = *(const bf16x8*)&Vs[(mt * 16 + l) * 72 + quad * 8];
      bf16x8 av1 = *(const bf16x8*)&Vs[(mt * 16 + l) * 72 + 32 + quad * 8];
      oacc[mt] = __builtin_amdgcn_mfma_f32_16x16x32_bf16(av0, bp0, oacc[mt], 0, 0, 0);
      oacc[mt] = __builtin_amdgcn_mfma_f32_16x16x32_bf16(av1, bp1, oacc[mt], 0, 0, 0);
    }
  }

  float l0 = __shfl(lrun[0], srcl, 64), l1 = __shfl(lrun[1], srcl, 64);
  float l2 = __shfl(lrun[2], srcl, 64), l3 = __shfl(lrun[3], srcl, 64);
  float lq = (rsel == 0) ? l0 : (rsel == 1) ? l1 : (rsel == 2) ? l2 : l3;
  float linv = 1.f / lq;
  bf16* obase = o + ((size_t)(b * kS + qt * 64 + w * 16 + l)) * kD + h * kHD + quad * 4;
#pragma unroll
  for (int mt = 0; mt < 4; ++mt) {
    bf16x4 ov;
#pragma unroll
    for (int rr = 0; rr < 4; ++rr) ov[rr] = (bf16)(oacc[mt][rr] * linv);
    *(bf16x4*)(obase + mt * 16) = ov;
  }
}

// ---------------- zero the small counters ----------------
__global__ void zero_kernel(int* counts, float* sumg, float* sump) {
  int i = threadIdx.x;
  if (i < kE) { counts[i] = 0; sumg[i] = 0.f; sump[i] = 0.f; }
}

// ---------------- Gate phase A: fp32 logits, no atomics. 4 tokens/block ----------------
__global__ __launch_bounds__(256) void gate_logits_kernel(const float* __restrict__ h,
                                                          const float* __restrict__ ffnw,
                                                          const float* __restrict__ rstd,
                                                          const float* __restrict__ gw,
                                                          float* __restrict__ logits) {
  int w = threadIdx.x >> 6, lane = threadIdx.x & 63;
  int t = blockIdx.x * 4 + w;
  int e = lane >> 3, c = lane & 7;
  const float4* hp = (const float4*)(h + (size_t)t * kD + c * 128);
  const float4* wp = (const float4*)(ffnw + c * 128);
  const float4* gp = (const float4*)(gw + (size_t)e * kD + c * 128);
  float sum = 0.f;
#pragma unroll 8
  for (int i = 0; i < 32; ++i) {
    float4 a = hp[i], b = wp[i], g4 = gp[i];
    sum += a.x * b.x * g4.x + a.y * b.y * g4.y + a.z * b.z * g4.z + a.w * b.w * g4.w;
  }
  sum += __shfl_xor(sum, 1, 64);
  sum += __shfl_xor(sum, 2, 64);
  sum += __shfl_xor(sum, 4, 64);
  if (c == 0) logits[(size_t)t * kE + e] = sum * rstd[t];
}

// ---------------- Gate phase B: top-2 + softmax + block-reduced stats ----------------
__global__ __launch_bounds__(256) void gate_topk_kernel(const float* __restrict__ logits,
                                                        int* __restrict__ counts,
                                                        float* __restrict__ sumg, float* __restrict__ sump,
                                                        int* __restrict__ top_idx, float* __restrict__ top_gate) {
  __shared__ int cnt_s[kE];
  __shared__ float sg_s[kE], sp_s[kE];
  int tid = threadIdx.x;
  if (tid < kE) { cnt_s[tid] = 0; sg_s[tid] = 0.f; sp_s[tid] = 0.f; }
  __syncthreads();
  int t = blockIdx.x * 256 + tid;
  const float4* lp = (const float4*)(logits + (size_t)t * kE);
  float4 la = lp[0], lb = lp[1];
  float l[kE] = {la.x, la.y, la.z, la.w, lb.x, lb.y, lb.z, lb.w};
  int i1 = 0;
#pragma unroll
  for (int i = 1; i < kE; ++i) if (l[i] > l[i1]) i1 = i;
  int i2 = (i1 == 0) ? 1 : 0;
#pragma unroll
  for (int i = 0; i < kE; ++i) if (i != i1 && l[i] > l[i2]) i2 = i;
  float e2 = __expf(l[i2] - l[i1]);
  float g1 = 1.f / (1.f + e2);
  float g2 = e2 / (1.f + e2);
  float pm = l[i1];
  float pr[kE], ps = 0.f;
#pragma unroll
  for (int i = 0; i < kE; ++i) { pr[i] = __expf(l[i] - pm); ps += pr[i]; }
  float pinv = 1.f / ps;
#pragma unroll
  for (int i = 0; i < kE; ++i) atomicAdd(&sp_s[i], pr[i] * pinv);
  atomicAdd(&sg_s[i1], g1);
  atomicAdd(&sg_s[i2], g2);
  atomicAdd(&cnt_s[i1], 1);
  atomicAdd(&cnt_s[i2], 1);
  top_idx[2 * t] = i1; top_idx[2 * t + 1] = i2;
  top_gate[2 * t] = g1; top_gate[2 * t + 1] = g2;
  __syncthreads();
  if (tid < kE) {
    atomicAdd(&counts[tid], cnt_s[tid]);
    atomicAdd(&sumg[tid], sg_s[tid]);
    atomicAdd(&sump[tid], sp_s[tid]);
  }
}

// ---------------- offsets + cursors + aux loss ----------------
__global__ void offsets_aux_kernel(const int* counts, int* offs, int* cur,
                                   const float* sumg, const float* sump, float* out_aux) {
  if (threadIdx.x == 0 && blockIdx.x == 0) {
    int acc = 0;
    for (int e = 0; e < kE; ++e) { offs[e] = acc; cur[e] = acc; acc += counts[e]; }
    float aux = 0.f;
    for (int e = 0; e < kE; ++e) aux += (sumg[e] / (float)kT) * (sump[e] / (float)kT);
    out_aux[0] = (float)kE * aux;
  }
}

// ---------------- scatter token->slot (block-scan, 8 atomics/block) ----------------
__global__ __launch_bounds__(256) void scatter_kernel(const int* __restrict__ top_idx,
                                                      const float* __restrict__ top_gate,
                                                      int* __restrict__ cur,
                                                      int* __restrict__ assign_token,
                                                      float* __restrict__ assign_gate,
                                                      int* __restrict__ tok_slot) {
  __shared__ int cnt_s[kE], base_s[kE];
  int tid = threadIdx.x;
  if (tid < kE) cnt_s[tid] = 0;
  __syncthreads();
  int id = blockIdx.x * 256 + tid;
  int e = top_idx[id];
  int rank = atomicAdd(&cnt_s[e], 1);
  __syncthreads();
  if (tid < kE) base_s[tid] = atomicAdd(&cur[tid], cnt_s[tid]);
  __syncthreads();
  int slot = base_s[e] + rank;
  assign_token[slot] = id >> 1;
  assign_gate[slot] = top_gate[id];
  tok_slot[id] = slot;
}

// ---------------- silu(g)*u elementwise, in-place into g ----------------
__global__ __launch_bounds__(256) void silu_mul_kernel(bf16* __restrict__ gbuf, const bf16* __restrict__ ubuf) {
  size_t id = ((size_t)blockIdx.x * 256 + threadIdx.x) * 8;
  bf16x8 gv = *(bf16x8*)(gbuf + id);
  bf16x8 uv = *(const bf16x8*)(ubuf + id);
  bf16x8 ov;
#pragma unroll
  for (int i = 0; i < 8; ++i) {
    float gf = (float)gv[i], uf = (float)uv[i];
    float sig = 1.f / (1.f + __expf(-gf));
    ov[i] = (bf16)(gf * sig * uf);
  }
  *(bf16x8*)(gbuf + id) = ov;
}

// ---------------- final: out = h + down[slot0] + down[slot1] (gates pre-applied) ----------------
__global__ __launch_bounds__(256) void final_kernel(const float* __restrict__ h,
                                                    const float* __restrict__ down,
                                                    const int* __restrict__ tok_slot,
                                                    float* __restrict__ out) {
  int t = blockIdx.x, tid = threadIdx.x;
  int s0 = tok_slot[2 * t], s1 = tok_slot[2 * t + 1];
  const float4* hp = (const float4*)(h + (size_t)t * kD);
  const float4* d0 = (const float4*)(down + (size_t)s0 * kD);
  const float4* d1 = (const float4*)(down + (size_t)s1 * kD);
  float4 a = hp[tid], b0 = d0[tid], b1 = d1[tid];
  float4 rv;
  rv.x = a.x + b0.x + b1.x;
  rv.y = a.y + b0.y + b1.y;
  rv.z = a.z + b0.z + b1.z;
  rv.w = a.w + b0.w + b1.w;
  ((float4*)(out + (size_t)t * kD))[tid] = rv;
}

extern "C" void kernel_launch(void* const* d_in, const int* in_sizes, int n_in,
                              void* d_out, int out_size, void* d_ws, size_t ws_size,
                              hipStream_t stream) {
  const float* x = (const float*)d_in[0];
  const float* wq = (const float*)d_in[1];
  const float* wk = (const float*)d_in[2];
  const float* wv = (const float*)d_in[3];
  const float* wo = (const float*)d_in[4];
  const float* attn_w = (const float*)d_in[5];
  const float* ffn_w = (const float*)d_in[6];
  const float* gate_w = (const float*)d_in[7];
  const float* wg = (const float*)d_in[8];
  const float* wu = (const float*)d_in[9];
  const float* wd = (const float*)d_in[10];
  float* out = (float*)d_out;

  char* ws = (char*)d_ws;
  size_t off = 0;
  auto alloc = [&](size_t bytes) -> void* {
    void* p = ws + off;
    off = (off + bytes + 255) & ~(size_t)255;
    return p;
  };
  bf16* xn = (bf16*)alloc((size_t)kT * kD * 2);
  bf16* qb = (bf16*)alloc((size_t)kT * kD * 2);
  bf16* kb = (bf16*)alloc((size_t)kT * kD * 2);
  bf16* vtb = (bf16*)alloc((size_t)kT * kD * 2);  // V^T: [(b*1024+h*64+d)][s]
  bf16* attn_o = (bf16*)alloc((size_t)kT * kD * 2);
  float* hbuf = (float*)alloc((size_t)kT * kD * 4);
  bf16* hn = (bf16*)alloc((size_t)kT * kD * 2);
  float* rstd = (float*)alloc((size_t)kT * 4);
  float* logits = (float*)alloc((size_t)kT * kE * 4);
  int* counts = (int*)alloc(kE * 4);
  int* cur = (int*)alloc(kE * 4);
  int* offs = (int*)alloc(kE * 4);
  float* sumg = (float*)alloc(kE * 4);
  float* sump = (float*)alloc(kE * 4);
  int* top_idx = (int*)alloc((size_t)kSlots * 4);
  float* top_gate = (float*)alloc((size_t)kSlots * 4);
  int* assign_token = (int*)alloc((size_t)kSlots * 4);
  float* assign_gate = (float*)alloc((size_t)kSlots * 4);
  int* tok_slot = (int*)alloc((size_t)kSlots * 4);
  bf16* gbuf = (bf16*)alloc((size_t)kSlots * kHID * 2);
  bf16* ubuf = (bf16*)alloc((size_t)kSlots * kHID * 2);
  float* down = (float*)alloc((size_t)kSlots * kD * 4);
  (void)ws_size; (void)n_in; (void)in_sizes; (void)out_size;

  // 1. zero counters
  zero_kernel<<<1, 64, 0, stream>>>(counts, sumg, sump);
  // 2. rmsnorm(x) -> xn (bf16)
  rmsnorm_kernel<<<kT, 256, 0, stream>>>(x, attn_w, xn, nullptr);
  // 3. fused QKV GEMM -> qb, kb (bf16) and V^T (bf16, transposed store)
  gemm_bt<<<dim3(kD / BN, kT / BM, 3), 256, 0, stream>>>(
      xn, kD, wq, wk, wv, 0, kD, qb, kb, vtb, kD, 1, 1, kT, kD, kD,
      nullptr, nullptr, nullptr, nullptr, nullptr);
  // 4. RoPE in-place on q,k (bf16)
  rope_kernel<<<(kT * kNH * 32) / 256, 256, 0, stream>>>(qb, kb);
  // 5. MFMA causal flash attention -> attn_o (bf16)
  attn_mfma_kernel<<<dim3(kS / 64, kNH, kB), 256, 0, stream>>>(qb, kb, vtb, attn_o);
  // 6. O-proj + residual(x) -> hbuf (fp32)
  gemm_bt<<<dim3(kD / BN, kT / BM, 1), 256, 0, stream>>>(
      attn_o, kD, wo, nullptr, nullptr, 0, kD, hbuf, nullptr, nullptr, kD, 0, 0, kT, kD, kD,
      nullptr, nullptr, nullptr, nullptr, x);
  // 7. rmsnorm(h) -> hn (bf16) + rstd
  rmsnorm_kernel<<<kT, 256, 0, stream>>>(hbuf, ffn_w, hn, rstd);
  // 8a. gate logits (fp32, no atomics)
  gate_logits_kernel<<<kT / 4, 256, 0, stream>>>(hbuf, ffn_w, rstd, gate_w, logits);
  // 8b. top-2 + stats (block-reduced)
  gate_topk_kernel<<<kT / 256, 256, 0, stream>>>(logits, counts, sumg, sump, top_idx, top_gate);
  // 9. offsets/cursors + aux loss -> d_out[T*D]
  offsets_aux_kernel<<<1, 1, 0, stream>>>(counts, offs, cur, sumg, sump, out + (size_t)kT * kD);
  // 10. scatter assignments (block-scan)
  scatter_kernel<<<kSlots / 256, 256, 0, stream>>>(top_idx, top_gate, cur, assign_token, assign_gate, tok_slot);
  // 11. expert gate-proj and up-proj GEMMs (gathered rows of hn)
  gemm_bt<<<dim3(kHID / BN, kT / BM, kE), 256, 0, stream>>>(
      hn, kD, wg, nullptr, nullptr, (long)kHID * kD, kD, gbuf, nullptr, nullptr, kHID, 1, 0, kT, kHID, kD,
      counts, offs, assign_token, nullptr, nullptr);
  gemm_bt<<<dim3(kHID / BN, kT / BM, kE), 256, 0, stream>>>(
      hn, kD, wu, nullptr, nullptr, (long)kHID * kD, kD, ubuf, nullptr, nullptr, kHID, 1, 0, kT, kHID, kD,
      counts, offs, assign_token, nullptr, nullptr);
  // 12. silu(g)*u -> gbuf in place
  silu_mul_kernel<<<((size_t)kSlots * kHID / 8) / 256, 256, 0, stream>>>(gbuf, ubuf);
  // 13. down-proj GEMM, scaled by gate per row -> down (fp32)
  gemm_bt<<<dim3(kD / BN, kT / BM, kE), 256, 0, stream>>>(
      gbuf, kHID, wd, nullptr, nullptr, (long)kD * kHID, kHID, down, nullptr, nullptr, kD, 0, 0, kT, kD, kHID,
      counts, offs, nullptr, assign_gate, nullptr);
  // 14. out = h + down[s0] + down[s1]
  final_kernel<<<kT, 256, 0, stream>>>(hbuf, down, tok_slot, out);
}